// Round 9
// baseline (170.505 us; speedup 1.0000x reference)
//
#include <hip/hip_runtime.h>
#include <math.h>

// v14: CODE-SIZE test -- rolled loops (~3KB body) instead of full unroll.
//
// Evidence: 7 structures (LDS-staged x4, zero-LDS, ILP-interleaved) ALL at
// 46-50us kernel, VALUBusy pinned 39%. Issue model: ~5-6k cyc/wave x 8
// waves/SIMD = ~20us chip VALU time = VALUBusy x wall (18us) -- consistent.
// So 61% of SIMD time issues NOTHING despite 3+ resident waves of pure ILP.
// No measured pipe explains it. The one never-varied shared attribute:
// all versions are fully-unrolled 10-15KB straight-line code, executed
// once per wave = the instruction-fetch-starvation shape (invisible in
// all collected counters). v14 = v8's exact math with:
//  (1) batch loop (2) and row loop (5) ROLLED (#pragma unroll 1);
//      j-body (5 positions) stays unrolled -> ~3KB hot loop, executed
//      10x per wave -> I-cache resident after iter 1.
//  (2) runtime row indices (3 cndmask/iter); rows re-read per i
//      (75 vs 55 ds_read_b64 -- LDS pipe has headroom).
//  (3) log-pairing made i-local: (z0*z1),(z2*z3),(z4) -> 15 logs vs 13.
// Fork: I-fetch binder -> 22-30us kernel; flat -> declare practical floor.

typedef float v2f __attribute__((ext_vector_type(2)));

#define SREAD(x) __int_as_float(__builtin_amdgcn_readfirstlane(__float_as_int(x)))
#define WAITVM(N) asm volatile("s_waitcnt vmcnt(" #N ")" ::: "memory")
#define MEMFENCE() asm volatile("" ::: "memory")

__device__ __forceinline__ float dpp_swap1_f(float x) {      // lane ^ 1
    return __int_as_float(__builtin_amdgcn_mov_dpp(__float_as_int(x), 0xB1, 0xF, 0xF, true));
}
__device__ __forceinline__ float dpp_swap2_f(float x) {      // lane ^ 2
    return __int_as_float(__builtin_amdgcn_mov_dpp(__float_as_int(x), 0x4E, 0xF, 0xF, true));
}
__device__ __forceinline__ unsigned dpp_swap1_u(unsigned x) {
    return (unsigned)__builtin_amdgcn_mov_dpp((int)x, 0xB1, 0xF, 0xF, true);
}
__device__ __forceinline__ unsigned dpp_swap2_u(unsigned x) {
    return (unsigned)__builtin_amdgcn_mov_dpp((int)x, 0x4E, 0xF, 0xF, true);
}

__device__ __forceinline__ void gload16(const float* g, float* l) {
    __builtin_amdgcn_global_load_lds(
        (const __attribute__((address_space(1))) void*)g,
        (__attribute__((address_space(3))) void*)l, 16, 0, 0);
}
__device__ __forceinline__ void gload4(const float* g, float* l) {
    __builtin_amdgcn_global_load_lds(
        (const __attribute__((address_space(1))) void*)g,
        (__attribute__((address_space(3))) void*)l, 4, 0, 0);
}

__global__ __launch_bounds__(64) void CNN2D_37495064494620_kernel(
    const float* __restrict__ v,
    const float* __restrict__ cw,   // [4,1,3,3]
    const float* __restrict__ cb,   // [4]
    const float* __restrict__ dw,   // [4,1,2,2]
    const float* __restrict__ db,   // [1]
    float* __restrict__ out,        // [2*B]
    int B)
{
    const int lane = threadIdx.x;         // one wave per block
    const int q    = lane & 1;            // conv-row parity
    const int h    = (lane >> 1) & 1;     // filter-pair owner (f0,f1 | f2,f3)
    const int g    = lane >> 2;           // sample within each 16-sample batch

    __shared__ __align__(16) float sm[3200];   // 2 batches x 16 samples x 100

    // ---- stage both batches up front: 14 gload_lds ----
    const float* gbp = v + (size_t)blockIdx.x * 3200;
    #pragma unroll
    for (int k = 0; k < 6; ++k)
        gload16(gbp + k * 256 + lane * 4, sm + k * 256);
    gload4(gbp + 1536 + lane, sm + 1536);
    MEMFENCE();                     // batch 0's 7 loads stay oldest
    #pragma unroll
    for (int k = 0; k < 6; ++k)
        gload16(gbp + 1600 + k * 256 + lane * 4, sm + 1600 + k * 256);
    gload4(gbp + 3136 + lane, sm + 3136);

    // ---- uniform weights -> SGPRs (overlap the VMEM flight); v8 verbatim ----
    float Wf[4][9];
    #pragma unroll
    for (int f = 0; f < 4; ++f)
        #pragma unroll
        for (int t = 0; t < 9; ++t)
            Wf[f][t] = SREAD(cw[f * 9 + t]);
    v2f Wsel[9];
    #pragma unroll
    for (int t = 0; t < 9; ++t)
        Wsel[t] = (v2f){ h ? Wf[2][t] : Wf[0][t], h ? Wf[3][t] : Wf[1][t] };
    const float cb0 = SREAD(cb[0]), cb1 = SREAD(cb[1]);
    const float cb2 = SREAD(cb[2]), cb3 = SREAD(cb[3]);
    const v2f Cbsel = (v2f){ h ? cb2 : cb0, h ? cb3 : cb1 };

    float Dw4[4][4];
    #pragma unroll
    for (int f = 0; f < 4; ++f)
        #pragma unroll
        for (int t = 0; t < 4; ++t)
            Dw4[f][t] = SREAD(dw[f * 4 + t]);
    const float Db = SREAD(db[0]);
    float Dkl[4];                         // this lane's tap kl = 2q+h
    #pragma unroll
    for (int f = 0; f < 4; ++f) {
        const float e01 = h ? Dw4[f][1] : Dw4[f][0];
        const float e23 = h ? Dw4[f][3] : Dw4[f][2];
        Dkl[f] = q ? e23 : e01;
    }
    const float Ds0 = h ? Dkl[2] : Dkl[0];   // own filter pair first
    const float Ds1 = h ? Dkl[3] : Dkl[1];
    const float Ds2 = h ? Dkl[0] : Dkl[2];
    const float Ds3 = h ? Dkl[1] : Dkl[3];

    // ---- rolled batch loop ----
    #pragma unroll 1
    for (int b = 0; b < 2; ++b) {
        if (b == 0) { WAITVM(7); }    // batch 0 landed; batch 1 in flight
        else        { WAITVM(0); }    // batch 1 landed (hidden by b=0 work)

        const float* my = sm + b * 1600 + g * 100;
        unsigned sb = 0u;
        float l2 = 0.0f;

        // ---- rolled row loop: 5 iterations, ~3KB hot body ----
        #pragma unroll 1
        for (int i = 0; i < 5; ++i) {
            // window rows (runtime, per-lane): r1 = 2i+q, r0/r2 wrap at edges
            const int r1 = 2 * i + q;
            int r0 = 2 * i - 1 + q;     // correct for q=1 at i=0 (gives 0)
            if (i == 0 && q == 0) r0 = 9;
            int r2 = 2 * i + 1 + q;     // correct for q=0 at i=4 (gives 9)
            if (i == 4 && q == 1) r2 = 0;

            float R0[10], R1[10], R2[10];
            {
                const float* p0 = my + r0 * 10;
                const float* p1 = my + r1 * 10;
                const float* p2 = my + r2 * 10;
                #pragma unroll
                for (int t = 0; t < 5; ++t) {
                    float2 x0 = *(const float2*)(p0 + 2 * t);
                    float2 x1 = *(const float2*)(p1 + 2 * t);
                    float2 x2 = *(const float2*)(p2 + 2 * t);
                    R0[2 * t] = x0.x; R0[2 * t + 1] = x0.y;
                    R1[2 * t] = x1.x; R1[2 * t + 1] = x1.y;
                    R2[2 * t] = x2.x; R2[2 * t + 1] = x2.y;
                }
            }

            float zj[5];                // this row-pair's 5 z values
            #pragma unroll
            for (int j = 0; j < 5; ++j) {
                v2f a0 = Cbsel, a1 = Cbsel;   // cols 2j, 2j+1; lane's 2 filters
                #pragma unroll
                for (int kc = 0; kc < 3; ++kc) {
                    const int cc0 = (2 * j + kc + 9) % 10;       // compile-time
                    const int cc1 = (2 * j + 1 + kc + 9) % 10;
                    {
                        const v2f x0 = (v2f){R0[cc0], R0[cc0]};
                        const v2f x1 = (v2f){R0[cc1], R0[cc1]};
                        a0 = __builtin_elementwise_fma(x0, Wsel[kc], a0);
                        a1 = __builtin_elementwise_fma(x1, Wsel[kc], a1);
                    }
                    {
                        const v2f x0 = (v2f){R1[cc0], R1[cc0]};
                        const v2f x1 = (v2f){R1[cc1], R1[cc1]};
                        a0 = __builtin_elementwise_fma(x0, Wsel[3 + kc], a0);
                        a1 = __builtin_elementwise_fma(x1, Wsel[3 + kc], a1);
                    }
                    {
                        const v2f x0 = (v2f){R2[cc0], R2[cc0]};
                        const v2f x1 = (v2f){R2[cc1], R2[cc1]};
                        a0 = __builtin_elementwise_fma(x0, Wsel[6 + kc], a0);
                        a1 = __builtin_elementwise_fma(x1, Wsel[6 + kc], a1);
                    }
                }
                // 2x2 maxpool: dc-merge packed, then cross-q via DPP
                const v2f m = __builtin_elementwise_max(a0, a1);
                const float Px = fmaxf(m.x, dpp_swap1_f(m.x));
                const float Py = fmaxf(m.y, dpp_swap1_f(m.y));
                // partner filter pair's pooled values via cross-h DPP
                const float Qx = dpp_swap2_f(Px);
                const float Qy = dpp_swap2_f(Py);
                // deconv: this lane's single tap kl = 2q+h
                float z = Db;
                z = fmaf(Px, Ds0, z);
                z = fmaf(Py, Ds1, z);
                z = fmaf(Qx, Ds2, z);
                z = fmaf(Qy, Ds3, z);
                zj[j] = z;              // static index (j unrolled)
            }

            // i-local log-pairing: (z0*z1), (z2*z3), z4 -> 3 logs/iter
            const float p01 = zj[0] * zj[1];
            const float p23 = zj[2] * zj[3];
            sb ^= __float_as_uint(p01);
            sb ^= __float_as_uint(p23);
            sb ^= __float_as_uint(zj[4]);
            l2 += __log2f(fabsf(p01));
            l2 += __log2f(fabsf(p23));
            l2 += __log2f(fabsf(zj[4]));
        }

        // quad combine: each lane contributed 25 of the sample's 100 z's
        l2 += dpp_swap1_f(l2);
        l2 += dpp_swap2_f(l2);
        sb ^= dpp_swap1_u(sb);
        sb ^= dpp_swap2_u(sb);

        const int s = blockIdx.x * 32 + b * 16 + g;
        const int r = lane & 3;
        if (r == 0)      out[s]     = (sb & 0x80000000u) ? -1.0f : 1.0f;
        else if (r == 1) out[B + s] = l2 * 0.69314718055994531f;
    }
}

extern "C" void kernel_launch(void* const* d_in, const int* in_sizes, int n_in,
                              void* d_out, int out_size, void* d_ws, size_t ws_size,
                              hipStream_t stream) {
    const float* v  = (const float*)d_in[0];
    const float* cw = (const float*)d_in[1];
    const float* cb = (const float*)d_in[2];
    const float* dw = (const float*)d_in[3];
    const float* db = (const float*)d_in[4];
    float* out = (float*)d_out;

    const int B = in_sizes[0] / 100;       // 262144
    const int grid = B / 32;               // 32 samples per one-wave block
    CNN2D_37495064494620_kernel<<<grid, 64, 0, stream>>>(v, cw, cb, dw, db, out, B);
}